// Round 5
// baseline (37.796 us; speedup 1.0000x reference)
//
#include <hip/hip_runtime.h>

// Comb filter: y[n] = x[n-D] + f*y[n-D], y[n]=0 for n<D.
// N = 16777216, D = 4096 -> 4096 independent chains of K = 4096 steps each.
// Chain c, step k: a_k = x[k*D + c]; y_0 = 0; y_{k+1} = f*y_k + a_k;
// output[k*D + c] = y_k.
//
// Two kernels:
//   K1 carry (float4, 512 blocks — unchanged, ~5.6 TB/s):
//       C_s = sum_j f^(SEGLEN-1-j) a_j per (segment, chain).
//   K2 scan+emit (SCALAR, 2048 blocks, 32 waves/CU):
//       Y_s = sum_{t<s} fL^(s-1-t) C_t  (order-free weighted sum, batched),
//       then 32-step replay writing y. 1 float/thread keeps VGPR ~32 so
//       occupancy is full; x re-read is L3-hot from K1.
// R4 lesson: xa[32] preload (170 VGPR, 8 waves/CU) serialized read->write
// per wave; K2 ran at ~2.7 TB/s effective. Scalar+full-occupancy overlaps
// the read and write streams across waves.

#define N_TOTAL 16777216
#define D       4096
#define K_STEPS (N_TOTAL / D)    // 4096
#define SEGS    128              // segments per chain
#define SEGLEN  (K_STEPS / SEGS) // 32 steps per segment
#define D4      (D / 4)          // 1024 float4 per k-row

// 2 MiB scratch in a device global (fully rewritten every call).
__device__ float g_carry[SEGS * D];

__global__ __launch_bounds__(256)
void comb_carry(const float* __restrict__ x, const float* __restrict__ fptr) {
    const float f = fptr[0];
    const int c4 = (blockIdx.x & 3) * 256 + threadIdx.x;  // 0..1023
    const int s  = blockIdx.x >> 2;                       // 0..127
    const float4* __restrict__ xp = (const float4*)x;
    const int base = s * SEGLEN * D4 + c4;

    float4 acc = make_float4(0.f, 0.f, 0.f, 0.f);
    #pragma unroll 8
    for (int k = 0; k < SEGLEN; ++k) {
        float4 a = xp[base + k * D4];
        acc.x = f * acc.x + a.x;
        acc.y = f * acc.y + a.y;
        acc.z = f * acc.z + a.z;
        acc.w = f * acc.w + a.w;
    }
    ((float4*)g_carry)[s * D4 + c4] = acc;
}

__global__ __launch_bounds__(256)
void comb_scan_emit(const float* __restrict__ x, const float* __restrict__ fptr,
                    float* __restrict__ out) {
    const float f = fptr[0];
    const int s = blockIdx.x >> 4;                        // 0..127
    const int c = (blockIdx.x & 15) * 256 + threadIdx.x;  // 0..4095

    // fL = f^SEGLEN via 5 squarings (SEGLEN = 32)
    float fL = f * f;
    fL = fL * fL;
    fL = fL * fL;
    fL = fL * fL;
    fL = fL * fL;
    const float fL2 = fL * fL;
    const float fL4 = fL2 * fL2;

    // Segment-start state, order-free weighted sum over earlier carries:
    //   Y_s = sum_{t=0}^{s-1} fL^(s-1-t) * C_t
    // iterated t downward, 4 independent accumulators, batched loads.
    const float* __restrict__ cp = g_carry;
    float Y0 = 0.f, Y1 = 0.f, Y2 = 0.f, Y3 = 0.f;
    float w = 1.f;
    int t = s - 1;
    #pragma unroll 4
    for (; t >= 3; t -= 4) {
        float C0 = cp[(t    ) * D + c];
        float C1 = cp[(t - 1) * D + c];
        float C2 = cp[(t - 2) * D + c];
        float C3 = cp[(t - 3) * D + c];
        const float w0 = w, w1 = w * fL, w2 = w * fL2, w3 = w1 * fL2;
        Y0 += w0 * C0;
        Y1 += w1 * C1;
        Y2 += w2 * C2;
        Y3 += w3 * C3;
        w = w * fL4;
    }
    for (; t >= 0; --t) {
        Y0 += w * cp[t * D + c];
        w *= fL;
    }
    float y = (Y0 + Y1) + (Y2 + Y3);

    // Replay exact recurrence from Y_s, write y. Fully unrolled; x loads are
    // independent of the y chain so the scheduler hoists them ahead.
    const int base = s * SEGLEN * D + c;
    #pragma unroll
    for (int k = 0; k < SEGLEN; ++k) {
        out[base + k * D] = y;
        y = f * y + x[base + k * D];
    }
}

extern "C" void kernel_launch(void* const* d_in, const int* in_sizes, int n_in,
                              void* d_out, int out_size, void* d_ws, size_t ws_size,
                              hipStream_t stream) {
    const float* x = (const float*)d_in[0];
    const float* f = (const float*)d_in[1];
    float* out = (float*)d_out;
    (void)in_sizes; (void)n_in; (void)d_ws; (void)ws_size; (void)out_size;

    dim3 blk(256);
    comb_carry<<<dim3(SEGS * 4), blk, 0, stream>>>(x, f);
    comb_scan_emit<<<dim3(SEGS * 16), blk, 0, stream>>>(x, f, out);
}